// Round 7
// baseline (135.629 us; speedup 1.0000x reference)
//
#include <hip/hip_runtime.h>
#include <math.h>

#define B_DIM    1024
#define IN_DIMS  512
#define OUT_DIMS 512
#define MOD_DIM  256
#define EPS_F    1e-8f
#define NBLOCKS  256u
#define LPC      520   // Bs row stride (bf16): 1040B -> bank step 4/row, 2-way (free)

typedef __attribute__((ext_vector_type(8))) short bf16x8;
typedef __attribute__((ext_vector_type(4))) float f32x4;
typedef unsigned short ush;

__device__ unsigned int g_arrive = 0;   // reset to 0 by last departer each call
__device__ unsigned int g_depart = 0;

__device__ __forceinline__ ush f2bf(float f) {
    union { float f; unsigned u; } c; c.f = f;
    unsigned r = c.u + 0x7fffu + ((c.u >> 16) & 1u);   // RNE
    return (ush)(r >> 16);
}
__device__ __forceinline__ float bf2f(ush h) {
    union { float f; unsigned u; } c; c.u = ((unsigned)h) << 16;
    return c.f;
}
// 8 fp32 -> hi/lo bf16x8 fragments (RNE both; protects sign(s)-sensitive epilogue)
__device__ __forceinline__ void split_f4(float4 a, float4 b, bf16x8& h, bf16x8& l) {
    float v0 = a.x, v1 = a.y, v2 = a.z, v3 = a.w;
    float v4 = b.x, v5 = b.y, v6 = b.z, v7 = b.w;
    ush h0 = f2bf(v0), h1 = f2bf(v1), h2 = f2bf(v2), h3 = f2bf(v3);
    ush h4 = f2bf(v4), h5 = f2bf(v5), h6 = f2bf(v6), h7 = f2bf(v7);
    h[0]=(short)h0; h[1]=(short)h1; h[2]=(short)h2; h[3]=(short)h3;
    h[4]=(short)h4; h[5]=(short)h5; h[6]=(short)h6; h[7]=(short)h7;
    l[0]=(short)f2bf(v0-bf2f(h0)); l[1]=(short)f2bf(v1-bf2f(h1));
    l[2]=(short)f2bf(v2-bf2f(h2)); l[3]=(short)f2bf(v3-bf2f(h3));
    l[4]=(short)f2bf(v4-bf2f(h4)); l[5]=(short)f2bf(v5-bf2f(h5));
    l[6]=(short)f2bf(v6-bf2f(h6)); l[7]=(short)f2bf(v7-bf2f(h7));
}

#define MFMA(A,B,C) __builtin_amdgcn_mfma_f32_16x16x32_bf16((A),(B),(C),0,0,0)

// ---------------------------------------------------------------------------
// ONE fused kernel, regular launch, grid (8 n-tiles, 32 m-tiles) = 256 blocks
// (1/CU, co-resident; proven at 105 KB LDS in round 6, here 71 KB).
//
// Phase B (all pre-barrier):
//   - stage bf16(weight[n0:n0+64, :]) -> LDS Bs  (phase C's B-operand: the
//     ONLY post-barrier traffic left is t_bf, so the L2-invalidate is cheap)
//   - per-block colsum of cols n0..n0+63 (L2-resident column slice)
//   - LDS-FREE split-bf16 mod GEMM: A/B fragments loaded straight from
//     global (lane pattern row=lane&15, k=quad*8 is 128B-coalesced), hi/lo
//     split in registers; 6 MFMA per 32-k step (hh+hl+lh)
//   - demod epilogue t = x*s*rsqrt(s^2*colsum+eps) -> t_bf (global)
// Grid barrier: fence(release) + arrive counter + spin + fence(acquire).
// Phase C: out = t_bf @ Bs^T + bias; A-frags direct from t_bf (bf16, 16B
//   loads), B from LDS. Depart counter: last block resets both counters.
// ---------------------------------------------------------------------------
__global__ __launch_bounds__(256, 1) void fused_all(
    const float* __restrict__ mods,    // [1024,256]
    const float* __restrict__ x,       // [1024,512]
    const float* __restrict__ weight,  // [512,512]
    const float* __restrict__ bias,    // [512]
    const float* __restrict__ mod_w,   // [512,256]
    const float* __restrict__ mod_b,   // [512]
    ush* __restrict__ t_bf,            // ws [1024,512]
    float* __restrict__ out)           // [1024,512]
{
    __shared__ ush    Bs[64 * LPC];    // 66560 B
    __shared__ float4 csm[16][16];     // 4096 B
    __shared__ float  colsum[64];

    const int tid = threadIdx.x;
    const int n0 = blockIdx.x * 64;    // 8 n-tiles
    const int m0 = blockIdx.y * 32;    // 32 m-tiles
    const int lane = tid & 63, wv = tid >> 6;
    const int wm = (wv >> 1) * 16, wn = (wv & 1) * 32;
    const int lr = lane & 15, lq = lane >> 4;

    // ---- stage Bs = bf16(weight[n0..n0+63][0..511])  (RNE) ----
    #pragma unroll
    for (int i = 0; i < 32; i++) {
        const int id = tid + i * 256;
        const int r = id >> 7, c4 = id & 127;
        float4 v = *(const float4*)&weight[(n0 + r) * IN_DIMS + c4 * 4];
        ushort4 h;
        h.x = f2bf(v.x); h.y = f2bf(v.y); h.z = f2bf(v.z); h.w = f2bf(v.w);
        *(ushort4*)&Bs[r * LPC + c4 * 4] = h;
    }

    // ---- per-block colsum of this block's 64 columns ----
    {
        const int c4 = tid & 15, rr = tid >> 4;
        float4 acc = {0.f, 0.f, 0.f, 0.f};
        #pragma unroll
        for (int it = 0; it < 32; it++) {
            const int row = rr + 16 * it;
            float4 v = *(const float4*)&weight[row * IN_DIMS + n0 + c4 * 4];
            acc.x += v.x * v.x; acc.y += v.y * v.y;
            acc.z += v.z * v.z; acc.w += v.w * v.w;
        }
        csm[rr][c4] = acc;
    }
    __syncthreads();
    if (tid < 16) {
        float4 s = csm[0][tid];
        #pragma unroll
        for (int j = 1; j < 16; j++) {
            float4 v = csm[j][tid];
            s.x += v.x; s.y += v.y; s.z += v.z; s.w += v.w;
        }
        *(float4*)&colsum[tid * 4] = s;
    }

    // ---- prefetch epilogue operands ----
    float xv[2][4], mb[2];
    #pragma unroll
    for (int j = 0; j < 2; j++) {
        const int gn = n0 + wn + 16 * j + lr;
        mb[j] = mod_b[gn];
        #pragma unroll
        for (int rr = 0; rr < 4; rr++)
            xv[j][rr] = x[(m0 + wm + lq * 4 + rr) * IN_DIMS + gn];
    }

    // ---- LDS-free split-bf16 mod GEMM: s-tile = mods @ mod_w^T ----
    const float* aP  = mods  + (m0 + wm + lr) * MOD_DIM;
    const float* b0P = mod_w + (n0 + wn + lr) * MOD_DIM;
    const float* b1P = mod_w + (n0 + wn + 16 + lr) * MOD_DIM;
    f32x4 acc[2] = {};
    #pragma unroll
    for (int ks = 0; ks < 8; ks++) {
        const int ko = ks * 32 + lq * 8;
        float4 a0 = *(const float4*)&aP[ko],  a1 = *(const float4*)&aP[ko + 4];
        float4 c0 = *(const float4*)&b0P[ko], c1 = *(const float4*)&b0P[ko + 4];
        float4 d0 = *(const float4*)&b1P[ko], d1 = *(const float4*)&b1P[ko + 4];
        bf16x8 ah, al, bh0, bl0, bh1, bl1;
        split_f4(a0, a1, ah, al);
        split_f4(c0, c1, bh0, bl0);
        split_f4(d0, d1, bh1, bl1);
        acc[0] = MFMA(ah, bh0, acc[0]);  acc[1] = MFMA(ah, bh1, acc[1]);
        acc[0] = MFMA(al, bh0, acc[0]);  acc[1] = MFMA(al, bh1, acc[1]);
        acc[0] = MFMA(ah, bl0, acc[0]);  acc[1] = MFMA(ah, bl1, acc[1]);
    }
    __syncthreads();   // colsum ready for all

    // ---- demod epilogue -> t_bf.  C/D: col=lane&15, row=(lane>>4)*4+reg ----
    #pragma unroll
    for (int j = 0; j < 2; j++) {
        const int ln = wn + 16 * j + lr;
        const int gn = n0 + ln;
        const float cs = colsum[ln];
        #pragma unroll
        for (int rr = 0; rr < 4; rr++) {
            const int gm = m0 + wm + lq * 4 + rr;
            const float s = acc[j][rr] + mb[j];
            const float tv = xv[j][rr] * s * rsqrtf(s * s * cs + EPS_F);
            t_bf[gm * IN_DIMS + gn] = f2bf(tv);
        }
    }

    // ---- grid barrier (release/acquire; t_bf crosses XCD L2s) ----
    __threadfence();
    __syncthreads();
    if (tid == 0) {
        __hip_atomic_fetch_add(&g_arrive, 1u, __ATOMIC_ACQ_REL,
                               __HIP_MEMORY_SCOPE_AGENT);
        while (__hip_atomic_load(&g_arrive, __ATOMIC_ACQUIRE,
                                 __HIP_MEMORY_SCOPE_AGENT) < NBLOCKS) {
            __builtin_amdgcn_s_sleep(2);
        }
    }
    __syncthreads();
    __threadfence();

    // ---- Phase C: out = t_bf @ Bs^T + bias (A direct-global, B in LDS) ----
    const ush* tP = t_bf + (m0 + wm + lr) * IN_DIMS;
    f32x4 acc2[2] = {};
    #pragma unroll
    for (int ks = 0; ks < 16; ks++) {
        const int ko = ks * 32 + lq * 8;
        bf16x8 a  = *(const bf16x8*)&tP[ko];
        bf16x8 b0 = *(const bf16x8*)&Bs[(wn +      lr) * LPC + ko];
        bf16x8 b1 = *(const bf16x8*)&Bs[(wn + 16 + lr) * LPC + ko];
        acc2[0] = MFMA(a, b0, acc2[0]);
        acc2[1] = MFMA(a, b1, acc2[1]);
    }

    #pragma unroll
    for (int j = 0; j < 2; j++) {
        const int gn = n0 + wn + 16 * j + lr;
        const float bv = bias[gn];
        #pragma unroll
        for (int rr = 0; rr < 4; rr++) {
            const int gm = m0 + wm + lq * 4 + rr;
            out[gm * OUT_DIMS + gn] = acc2[j][rr] + bv;
        }
    }

    // ---- depart: last block resets counters for the next graph replay ----
    __syncthreads();
    if (tid == 0) {
        unsigned old = __hip_atomic_fetch_add(&g_depart, 1u, __ATOMIC_ACQ_REL,
                                              __HIP_MEMORY_SCOPE_AGENT);
        if (old == NBLOCKS - 1) {
            __hip_atomic_store(&g_arrive, 0u, __ATOMIC_RELEASE,
                               __HIP_MEMORY_SCOPE_AGENT);
            __hip_atomic_store(&g_depart, 0u, __ATOMIC_RELEASE,
                               __HIP_MEMORY_SCOPE_AGENT);
        }
    }
}

extern "C" void kernel_launch(void* const* d_in, const int* in_sizes, int n_in,
                              void* d_out, int out_size, void* d_ws, size_t ws_size,
                              hipStream_t stream)
{
    const float* modulations = (const float*)d_in[0]; // [1024, 256]
    const float* x           = (const float*)d_in[1]; // [1024, 512]
    const float* weight      = (const float*)d_in[2]; // [512, 512]
    const float* bias        = (const float*)d_in[3]; // [512]
    const float* mod_w       = (const float*)d_in[4]; // [512, 256]
    const float* mod_b       = (const float*)d_in[5]; // [512]
    float* out = (float*)d_out;                       // [1024, 512]
    ush* t_bf = (ush*)d_ws;                           // 1 MB

    fused_all<<<dim3(8, 32), 256, 0, stream>>>(
        modulations, x, weight, bias, mod_w, mod_b, t_bf, out);
}

// Round 9
// 101.434 us; speedup vs baseline: 1.3371x; 1.3371x over previous
//
#include <hip/hip_runtime.h>
#include <math.h>

#define IN_DIMS  512
#define OUT_DIMS 512
#define MOD_DIM  256
#define EPS_F    1e-8f

typedef __attribute__((ext_vector_type(8))) short bf16x8;
typedef __attribute__((ext_vector_type(4))) float f32x4;
typedef unsigned short ush;

// LDS row strides (elements) -- all chosen so row-step ≡ 4 banks mod 32
// (2-way aliasing for 16-lane fragment groups = free per m136)
#define SA   264   // Amh/Aml (ush)
#define SS   516   // s_buf (fp32)
#define ST   520   // t_all (ush)
#define SW   72    // Ws (ush)

__device__ __forceinline__ ush f2bf(float f) {
    union { float f; unsigned u; } c; c.f = f;
    unsigned r = c.u + 0x7fffu + ((c.u >> 16) & 1u);   // RNE
    return (ush)(r >> 16);
}
__device__ __forceinline__ float bf2f(ush h) {
    union { float f; unsigned u; } c; c.u = ((unsigned)h) << 16;
    return c.f;
}
// 8 fp32 -> hi/lo bf16x8 (RNE both; protects the sign(s)-sensitive epilogue)
__device__ __forceinline__ void split_f4(float4 a, float4 b, bf16x8& h, bf16x8& l) {
    ush h0 = f2bf(a.x), h1 = f2bf(a.y), h2 = f2bf(a.z), h3 = f2bf(a.w);
    ush h4 = f2bf(b.x), h5 = f2bf(b.y), h6 = f2bf(b.z), h7 = f2bf(b.w);
    h[0]=(short)h0; h[1]=(short)h1; h[2]=(short)h2; h[3]=(short)h3;
    h[4]=(short)h4; h[5]=(short)h5; h[6]=(short)h6; h[7]=(short)h7;
    l[0]=(short)f2bf(a.x-bf2f(h0)); l[1]=(short)f2bf(a.y-bf2f(h1));
    l[2]=(short)f2bf(a.z-bf2f(h2)); l[3]=(short)f2bf(a.w-bf2f(h3));
    l[4]=(short)f2bf(b.x-bf2f(h4)); l[5]=(short)f2bf(b.y-bf2f(h5));
    l[6]=(short)f2bf(b.z-bf2f(h6)); l[7]=(short)f2bf(b.w-bf2f(h7));
}

#define MFMA(A,B,C) __builtin_amdgcn_mfma_f32_16x16x32_bf16((A),(B),(C),0,0,0)

// ---------------------------------------------------------------------------
// ONE regular dispatch, NO grid sync of any kind.
// 64 blocks x 1024 threads (16 waves). Block b owns batch rows m0=b*16..+16
// end-to-end:
//   P1: mods[16,256] -> LDS hi/lo bf16
//   P2: full-width mod GEMM: each wave takes a 32-col n-slice of all 512
//       in-dims; mod_w fragments loaded direct from global, split in regs
//       (3 MFMA per k-step: hh+hl+lh). s (pre-demod) -> s_buf LDS (fp32).
//   P3: full colsum[512] = sum_o W[o,i]^2 (block reads all of weight from
//       L2 -- redundant per block by design; 8 blocks/XCD share L2 copy)
//   P4: t[16,512] = x*s*rsqrt(s^2*colsum+eps) -> t_all LDS (bf16). t never
//       touches global memory; d_ws unused.
//   P5: out-GEMM streamed over 8 i-tiles of 64: stage bf16(W[:,i-tile])
//       into LDS Ws (64KB-ish region), 4 MFMA/wave/tile, block-local
//       barriers only.
//   P6: out = acc + bias.
// LDS total 158720 B (<160 KiB). 1 block/CU on 64 CUs; 2 waves/SIMD.
// ---------------------------------------------------------------------------
__global__ __launch_bounds__(1024, 1) void fused_rowband(
    const float* __restrict__ mods,    // [1024,256]
    const float* __restrict__ x,       // [1024,512]
    const float* __restrict__ weight,  // [512,512]
    const float* __restrict__ bias,    // [512]
    const float* __restrict__ mod_w,   // [512,256]
    const float* __restrict__ mod_b,   // [512]
    float* __restrict__ out)           // [1024,512]
{
    __shared__ __align__(16) char smem[158720];
    float* s_buf  = (float*)smem;                    // 16*516*4 = 33024
    ush*   t_all  = (ush*)(smem + 33024);            // 16*520*2 = 16640
    float* colsum = (float*)(smem + 49664);          // 2048
    ush*   Amh    = (ush*)(smem + 51712);            // 16*264*2 = 8448
    ush*   Aml    = (ush*)(smem + 60160);            // 8448
    float4* csm   = (float4*)(smem + 68608);         // 8*128*16 = 16384
    ush*   Ws     = (ush*)(smem + 84992);            // 512*72*2 = 73728 -> 158720

    const int tid  = threadIdx.x;
    const int m0   = blockIdx.x * 16;
    const int lane = tid & 63, wv = tid >> 6;        // 16 waves
    const int lr = lane & 15, lq = lane >> 4;

    // ---------------- P1: stage mods -> hi/lo bf16 LDS ----------------
    {
        const int r = tid >> 6, c4 = tid & 63;       // 16 rows x 64 quads
        float4 v = *(const float4*)&mods[(m0 + r) * MOD_DIM + c4 * 4];
        ushort4 h, l;
        h.x = f2bf(v.x); l.x = f2bf(v.x - bf2f(h.x));
        h.y = f2bf(v.y); l.y = f2bf(v.y - bf2f(h.y));
        h.z = f2bf(v.z); l.z = f2bf(v.z - bf2f(h.z));
        h.w = f2bf(v.w); l.w = f2bf(v.w - bf2f(h.w));
        *(ushort4*)&Amh[r * SA + c4 * 4] = h;
        *(ushort4*)&Aml[r * SA + c4 * 4] = l;
    }
    __syncthreads();

    // ---------------- P2: mod GEMM, wave n-slice = wv*32 ----------------
    f32x4 sacc[2] = {};
    {
        const float* bP0 = mod_w + (wv * 32 +      lr) * MOD_DIM;
        const float* bP1 = mod_w + (wv * 32 + 16 + lr) * MOD_DIM;
        #pragma unroll
        for (int ks = 0; ks < 8; ks++) {
            const int ko = ks * 32 + lq * 8;
            bf16x8 ah = *(bf16x8*)&Amh[lr * SA + ko];
            bf16x8 al = *(bf16x8*)&Aml[lr * SA + ko];
            float4 p0 = *(const float4*)&bP0[ko], p1 = *(const float4*)&bP0[ko + 4];
            float4 q0 = *(const float4*)&bP1[ko], q1 = *(const float4*)&bP1[ko + 4];
            bf16x8 bh0, bl0, bh1, bl1;
            split_f4(p0, p1, bh0, bl0);
            split_f4(q0, q1, bh1, bl1);
            sacc[0] = MFMA(ah, bh0, sacc[0]);  sacc[1] = MFMA(ah, bh1, sacc[1]);
            sacc[0] = MFMA(al, bh0, sacc[0]);  sacc[1] = MFMA(al, bh1, sacc[1]);
            sacc[0] = MFMA(ah, bl0, sacc[0]);  sacc[1] = MFMA(ah, bl1, sacc[1]);
        }
        // s (pre-demod) -> s_buf. C/D: col(n)=lr, row(m)=lq*4+reg
        #pragma unroll
        for (int j = 0; j < 2; j++) {
            const int n = wv * 32 + 16 * j + lr;
            const float mbv = mod_b[n];
            #pragma unroll
            for (int rr = 0; rr < 4; rr++)
                s_buf[(lq * 4 + rr) * SS + n] = sacc[j][rr] + mbv;
        }
    }

    // ---------------- P3a: colsum partials (full weight read) ----------------
    {
        const int c4 = tid & 127, rg = tid >> 7;     // 128 quads x 8 row-groups
        float4 acc = {0.f, 0.f, 0.f, 0.f};
        #pragma unroll
        for (int p = 0; p < 64; p++) {
            const int row = rg + 8 * p;
            float4 v = *(const float4*)&weight[row * IN_DIMS + c4 * 4];
            acc.x += v.x * v.x; acc.y += v.y * v.y;
            acc.z += v.z * v.z; acc.w += v.w * v.w;
        }
        csm[rg * 128 + c4] = acc;
    }
    __syncthreads();
    // ---------------- P3b: reduce -> colsum[512] ----------------
    if (tid < 128) {
        float4 s = csm[tid];
        #pragma unroll
        for (int r = 1; r < 8; r++) {
            float4 v = csm[r * 128 + tid];
            s.x += v.x; s.y += v.y; s.z += v.z; s.w += v.w;
        }
        *(float4*)&colsum[tid * 4] = s;
    }
    __syncthreads();

    // ---------------- P4: t_all = x*s*rsqrt(s^2*colsum+eps) (bf16) ----------------
    {
        const int m = tid >> 6, k8 = tid & 63;       // 16 rows x 64 chunks
        float4 xa = *(const float4*)&x[(m0 + m) * IN_DIMS + k8 * 8];
        float4 xb = *(const float4*)&x[(m0 + m) * IN_DIMS + k8 * 8 + 4];
        float4 sa = *(const float4*)&s_buf[m * SS + k8 * 8];
        float4 sb = *(const float4*)&s_buf[m * SS + k8 * 8 + 4];
        float4 ca = *(const float4*)&colsum[k8 * 8];
        float4 cb = *(const float4*)&colsum[k8 * 8 + 4];
        bf16x8 t;
        t[0] = (short)f2bf(xa.x * sa.x * rsqrtf(sa.x * sa.x * ca.x + EPS_F));
        t[1] = (short)f2bf(xa.y * sa.y * rsqrtf(sa.y * sa.y * ca.y + EPS_F));
        t[2] = (short)f2bf(xa.z * sa.z * rsqrtf(sa.z * sa.z * ca.z + EPS_F));
        t[3] = (short)f2bf(xa.w * sa.w * rsqrtf(sa.w * sa.w * ca.w + EPS_F));
        t[4] = (short)f2bf(xb.x * sb.x * rsqrtf(sb.x * sb.x * cb.x + EPS_F));
        t[5] = (short)f2bf(xb.y * sb.y * rsqrtf(sb.y * sb.y * cb.y + EPS_F));
        t[6] = (short)f2bf(xb.z * sb.z * rsqrtf(sb.z * sb.z * cb.z + EPS_F));
        t[7] = (short)f2bf(xb.w * sb.w * rsqrtf(sb.w * sb.w * cb.w + EPS_F));
        *(bf16x8*)&t_all[m * ST + k8 * 8] = t;
    }
    __syncthreads();

    // ---------------- P5: out-GEMM over 8 i-tiles of 64 ----------------
    f32x4 acc2[2] = {};
    const int sc4 = tid & 15, sr = tid >> 4;         // stage map: 16 quads x 64 rows
    #pragma unroll
    for (int it = 0; it < 8; it++) {
        const int i0 = it * 64;
        // stage Ws = bf16(weight[0:512][i0:i0+64])
        #pragma unroll
        for (int p = 0; p < 8; p++) {
            const int row = sr + 64 * p;
            float4 v = *(const float4*)&weight[row * IN_DIMS + i0 + sc4 * 4];
            ushort4 h;
            h.x = f2bf(v.x); h.y = f2bf(v.y); h.z = f2bf(v.z); h.w = f2bf(v.w);
            *(ushort4*)&Ws[row * SW + sc4 * 4] = h;
        }
        __syncthreads();
        // MFMA: wave o-slice = wv*32, 2 o-tiles x 2 k-steps
        #pragma unroll
        for (int j = 0; j < 2; j++) {
            const int orow = wv * 32 + 16 * j + lr;
            #pragma unroll
            for (int ks = 0; ks < 2; ks++) {
                const int ko = ks * 32 + lq * 8;
                bf16x8 a = *(bf16x8*)&t_all[lr * ST + i0 + ko];
                bf16x8 b = *(bf16x8*)&Ws[orow * SW + ko];
                acc2[j] = MFMA(a, b, acc2[j]);
            }
        }
        __syncthreads();   // before next tile overwrites Ws
    }

    // ---------------- P6: epilogue ----------------
    #pragma unroll
    for (int j = 0; j < 2; j++) {
        const int o = wv * 32 + 16 * j + lr;
        const float bv = bias[o];
        #pragma unroll
        for (int rr = 0; rr < 4; rr++) {
            const int gm = m0 + lq * 4 + rr;
            out[gm * OUT_DIMS + o] = acc2[j][rr] + bv;
        }
    }
}

extern "C" void kernel_launch(void* const* d_in, const int* in_sizes, int n_in,
                              void* d_out, int out_size, void* d_ws, size_t ws_size,
                              hipStream_t stream)
{
    const float* modulations = (const float*)d_in[0]; // [1024, 256]
    const float* x           = (const float*)d_in[1]; // [1024, 512]
    const float* weight      = (const float*)d_in[2]; // [512, 512]
    const float* bias        = (const float*)d_in[3]; // [512]
    const float* mod_w       = (const float*)d_in[4]; // [512, 256]
    const float* mod_b       = (const float*)d_in[5]; // [512]
    float* out = (float*)d_out;                       // [1024, 512]

    fused_rowband<<<64, 1024, 0, stream>>>(
        modulations, x, weight, bias, mod_w, mod_b, out);
}

// Round 10
// 100.535 us; speedup vs baseline: 1.3491x; 1.0089x over previous
//
#include <hip/hip_runtime.h>
#include <math.h>

#define IN_DIMS  512
#define OUT_DIMS 512
#define MOD_DIM  256
#define EPS_F    1e-8f

typedef __attribute__((ext_vector_type(8))) short bf16x8;
typedef __attribute__((ext_vector_type(4))) float f32x4;
typedef unsigned short ush;

// LDS row strides (elements); all give row-step ≡ 2-4 banks mod 32 (free 2-way)
#define SA 264    // Amh/Aml (ush)
#define SS 516    // s_buf (fp32)
#define ST 520    // t_all (ush)
#define SW 136    // Ws (ush) per 128-col tile: 272B/row -> 4-bank step

__device__ __forceinline__ ush f2bf(float f) {
    union { float f; unsigned u; } c; c.f = f;
    unsigned r = c.u + 0x7fffu + ((c.u >> 16) & 1u);   // RNE
    return (ush)(r >> 16);
}
__device__ __forceinline__ float bf2f(ush h) {
    union { float f; unsigned u; } c; c.u = ((unsigned)h) << 16;
    return c.f;
}
// 8 fp32 -> hi/lo bf16x8 (RNE both; protects the sign(s)-sensitive epilogue)
__device__ __forceinline__ void split_f4(float4 a, float4 b, bf16x8& h, bf16x8& l) {
    ush h0 = f2bf(a.x), h1 = f2bf(a.y), h2 = f2bf(a.z), h3 = f2bf(a.w);
    ush h4 = f2bf(b.x), h5 = f2bf(b.y), h6 = f2bf(b.z), h7 = f2bf(b.w);
    h[0]=(short)h0; h[1]=(short)h1; h[2]=(short)h2; h[3]=(short)h3;
    h[4]=(short)h4; h[5]=(short)h5; h[6]=(short)h6; h[7]=(short)h7;
    l[0]=(short)f2bf(a.x-bf2f(h0)); l[1]=(short)f2bf(a.y-bf2f(h1));
    l[2]=(short)f2bf(a.z-bf2f(h2)); l[3]=(short)f2bf(a.w-bf2f(h3));
    l[4]=(short)f2bf(b.x-bf2f(h4)); l[5]=(short)f2bf(b.y-bf2f(h5));
    l[6]=(short)f2bf(b.z-bf2f(h6)); l[7]=(short)f2bf(b.w-bf2f(h7));
}
// pack 8 fp32 -> 8 bf16 in a uint4 (16B LDS write)
__device__ __forceinline__ uint4 pack8(float4 a, float4 b) {
    uint4 u;
    u.x = (unsigned)f2bf(a.x) | ((unsigned)f2bf(a.y) << 16);
    u.y = (unsigned)f2bf(a.z) | ((unsigned)f2bf(a.w) << 16);
    u.z = (unsigned)f2bf(b.x) | ((unsigned)f2bf(b.y) << 16);
    u.w = (unsigned)f2bf(b.z) | ((unsigned)f2bf(b.w) << 16);
    return u;
}

#define MFMA(A,B,C) __builtin_amdgcn_mfma_f32_16x16x32_bf16((A),(B),(C),0,0,0)

// ---------------------------------------------------------------------------
// ONE regular dispatch, no grid sync. 64 blocks x 1024 thr (16 waves).
// Block owns batch rows m0..m0+15 end-to-end. vs round 9: every global-load
// chain is explicitly batched/prefetched so >=8-16 loads are in flight
// (round 9 was serialized at VGPR=64 -> 41 us latency-bound).
//   P1: mods -> hi/lo bf16 LDS          P2: mod GEMM (direct-global B frags)
//   P3: colsum via ping-pong batches    P4: t = x*s*rsqrt(s^2*cs+eps) -> LDS
//   P5: out GEMM, 4 tiles x 128 cols, reg-prefetch next tile during MFMA
// LDS 157952 B; Ws region aliases the P1-P4 transients.
// ---------------------------------------------------------------------------
__global__ __launch_bounds__(1024, 1) void fused_v10(
    const float* __restrict__ mods,    // [1024,256]
    const float* __restrict__ x,       // [1024,512]
    const float* __restrict__ weight,  // [512,512]
    const float* __restrict__ bias,    // [512]
    const float* __restrict__ mod_w,   // [512,256]
    const float* __restrict__ mod_b,   // [512]
    float* __restrict__ out)           // [1024,512]
{
    __shared__ __align__(16) char smem[157952];
    ush*   t_all  = (ush*)smem;                      // 16*520*2 = 16640
    float* colsum = (float*)(smem + 16640);          // 2048 -> 18688
    ush*   Ws     = (ush*)(smem + 18688);            // 512*136*2 = 139264 -> 157952
    // transients (alias inside Ws region; dead before first Ws write)
    float* s_buf  = (float*)(smem + 18688);          // 16*516*4 = 33024
    ush*   Amh    = (ush*)(smem + 51712);            // 8448
    ush*   Aml    = (ush*)(smem + 60160);            // 8448
    float4* csm   = (float4*)(smem + 68608);         // 16384 -> 84992

    const int tid  = threadIdx.x;
    const int m0   = blockIdx.x * 16;
    const int lane = tid & 63, wv = tid >> 6;        // 16 waves
    const int lr = lane & 15, lq = lane >> 4;

    // ---- early x prefetch (consumed in P4; latency hidden under P1-P3) ----
    const int pm = tid >> 6, pk8 = tid & 63;         // 16 rows x 64 chunks
    float4 xa = *(const float4*)&x[(m0 + pm) * IN_DIMS + pk8 * 8];
    float4 xb = *(const float4*)&x[(m0 + pm) * IN_DIMS + pk8 * 8 + 4];

    // ---------------- P1: mods -> hi/lo bf16 LDS ----------------
    {
        const int r = tid >> 6, c4 = tid & 63;
        float4 v = *(const float4*)&mods[(m0 + r) * MOD_DIM + c4 * 4];
        ushort4 h, l;
        h.x = f2bf(v.x); l.x = f2bf(v.x - bf2f(h.x));
        h.y = f2bf(v.y); l.y = f2bf(v.y - bf2f(h.y));
        h.z = f2bf(v.z); l.z = f2bf(v.z - bf2f(h.z));
        h.w = f2bf(v.w); l.w = f2bf(v.w - bf2f(h.w));
        *(ushort4*)&Amh[r * SA + c4 * 4] = h;
        *(ushort4*)&Aml[r * SA + c4 * 4] = l;
    }
    __syncthreads();

    // ---------------- P2: mod GEMM, wave n-slice = wv*32 ----------------
    {
        f32x4 sacc[2] = {};
        const float* bP0 = mod_w + (wv * 32 +      lr) * MOD_DIM;
        const float* bP1 = mod_w + (wv * 32 + 16 + lr) * MOD_DIM;
        #pragma unroll
        for (int ks = 0; ks < 8; ks++) {
            const int ko = ks * 32 + lq * 8;
            bf16x8 ah = *(bf16x8*)&Amh[lr * SA + ko];
            bf16x8 al = *(bf16x8*)&Aml[lr * SA + ko];
            float4 p0 = *(const float4*)&bP0[ko], p1 = *(const float4*)&bP0[ko + 4];
            float4 q0 = *(const float4*)&bP1[ko], q1 = *(const float4*)&bP1[ko + 4];
            bf16x8 bh0, bl0, bh1, bl1;
            split_f4(p0, p1, bh0, bl0);
            split_f4(q0, q1, bh1, bl1);
            sacc[0] = MFMA(ah, bh0, sacc[0]);  sacc[1] = MFMA(ah, bh1, sacc[1]);
            sacc[0] = MFMA(al, bh0, sacc[0]);  sacc[1] = MFMA(al, bh1, sacc[1]);
            sacc[0] = MFMA(ah, bl0, sacc[0]);  sacc[1] = MFMA(ah, bl1, sacc[1]);
        }
        // s -> s_buf.  C/D: col(n)=lr, row(m)=lq*4+reg
        #pragma unroll
        for (int j = 0; j < 2; j++) {
            const int n = wv * 32 + 16 * j + lr;
            const float mbv = mod_b[n];
            #pragma unroll
            for (int rr = 0; rr < 4; rr++)
                s_buf[(lq * 4 + rr) * SS + n] = sacc[j][rr] + mbv;
        }
    }

    // ------- P3a: colsum partials, ping-pong batches (8 loads in flight) -------
    {
        const int c4 = tid & 127, rg = tid >> 7;     // 128 quads x 8 row-groups
        const float* wp = weight + c4 * 4;
        float4 rr2[2][8];
        #pragma unroll
        for (int j = 0; j < 8; j++)                  // batch 0: rows rg + 64j
            rr2[0][j] = *(const float4*)&wp[(rg + 64 * j) * IN_DIMS];
        float4 a4 = {0.f, 0.f, 0.f, 0.f};
        #pragma unroll
        for (int g = 0; g < 8; g++) {                // batch g: rows rg+8g+64j
            const int cur = g & 1;
            if (g < 7) {
                #pragma unroll
                for (int j = 0; j < 8; j++)
                    rr2[cur ^ 1][j] =
                        *(const float4*)&wp[(rg + 8 * (g + 1) + 64 * j) * IN_DIMS];
            }
            #pragma unroll
            for (int j = 0; j < 8; j++) {
                float4 v = rr2[cur][j];
                a4.x += v.x * v.x; a4.y += v.y * v.y;
                a4.z += v.z * v.z; a4.w += v.w * v.w;
            }
        }
        csm[rg * 128 + c4] = a4;
    }
    __syncthreads();
    // ---------------- P3b: reduce -> colsum[512] ----------------
    if (tid < 128) {
        float4 s = csm[tid];
        #pragma unroll
        for (int r = 1; r < 8; r++) {
            float4 v = csm[r * 128 + tid];
            s.x += v.x; s.y += v.y; s.z += v.z; s.w += v.w;
        }
        *(float4*)&colsum[tid * 4] = s;
    }
    __syncthreads();

    // ---- P5 tile-0 register prefetch (latency hidden under P4 + barriers) ----
    const int c8 = tid & 15, r0 = tid >> 4;          // 16 col-chunks x 64 rows
    float4 pf[16];
    #pragma unroll
    for (int p = 0; p < 8; p++) {
        const int row = r0 + 64 * p;
        pf[2 * p]     = *(const float4*)&weight[row * IN_DIMS + c8 * 8];
        pf[2 * p + 1] = *(const float4*)&weight[row * IN_DIMS + c8 * 8 + 4];
    }

    // ---------------- P4: t_all = x*s*rsqrt(s^2*colsum+eps) ----------------
    {
        float4 sa = *(const float4*)&s_buf[pm * SS + pk8 * 8];
        float4 sb = *(const float4*)&s_buf[pm * SS + pk8 * 8 + 4];
        float4 ca = *(const float4*)&colsum[pk8 * 8];
        float4 cb = *(const float4*)&colsum[pk8 * 8 + 4];
        bf16x8 t;
        t[0] = (short)f2bf(xa.x * sa.x * rsqrtf(sa.x * sa.x * ca.x + EPS_F));
        t[1] = (short)f2bf(xa.y * sa.y * rsqrtf(sa.y * sa.y * ca.y + EPS_F));
        t[2] = (short)f2bf(xa.z * sa.z * rsqrtf(sa.z * sa.z * ca.z + EPS_F));
        t[3] = (short)f2bf(xa.w * sa.w * rsqrtf(sa.w * sa.w * ca.w + EPS_F));
        t[4] = (short)f2bf(xb.x * sb.x * rsqrtf(sb.x * sb.x * cb.x + EPS_F));
        t[5] = (short)f2bf(xb.y * sb.y * rsqrtf(sb.y * sb.y * cb.y + EPS_F));
        t[6] = (short)f2bf(xb.z * sb.z * rsqrtf(sb.z * sb.z * cb.z + EPS_F));
        t[7] = (short)f2bf(xb.w * sb.w * rsqrtf(sb.w * sb.w * cb.w + EPS_F));
        *(bf16x8*)&t_all[pm * ST + pk8 * 8] = t;
    }

    // ------- P5: out GEMM, 4 tiles x 128 cols, reg-prefetch next tile -------
    f32x4 acc2[2] = {};
    #pragma unroll
    for (int it = 0; it < 4; it++) {
        __syncthreads();   // it=0: s_buf reads done (Ws aliases it); else: prev MFMA done
        #pragma unroll
        for (int p = 0; p < 8; p++) {
            const int row = r0 + 64 * p;
            *(uint4*)&Ws[row * SW + c8 * 8] = pack8(pf[2 * p], pf[2 * p + 1]);
        }
        __syncthreads();
        if (it < 3) {      // prefetch tile it+1; latency overlaps MFMA below
            #pragma unroll
            for (int p = 0; p < 8; p++) {
                const int row = r0 + 64 * p;
                const int col = (it + 1) * 128 + c8 * 8;
                pf[2 * p]     = *(const float4*)&weight[row * IN_DIMS + col];
                pf[2 * p + 1] = *(const float4*)&weight[row * IN_DIMS + col + 4];
            }
        }
        #pragma unroll
        for (int j = 0; j < 2; j++) {
            const int orow = wv * 32 + 16 * j + lr;
            #pragma unroll
            for (int ks = 0; ks < 4; ks++) {
                const int ko = ks * 32 + lq * 8;
                bf16x8 a = *(bf16x8*)&t_all[lr * ST + it * 128 + ko];
                bf16x8 b = *(bf16x8*)&Ws[orow * SW + ko];
                acc2[j] = MFMA(a, b, acc2[j]);
            }
        }
    }

    // ---------------- P6: epilogue ----------------
    #pragma unroll
    for (int j = 0; j < 2; j++) {
        const int o = wv * 32 + 16 * j + lr;
        const float bv = bias[o];
        #pragma unroll
        for (int rr = 0; rr < 4; rr++) {
            const int gm = m0 + lq * 4 + rr;
            out[gm * OUT_DIMS + o] = acc2[j][rr] + bv;
        }
    }
}

extern "C" void kernel_launch(void* const* d_in, const int* in_sizes, int n_in,
                              void* d_out, int out_size, void* d_ws, size_t ws_size,
                              hipStream_t stream)
{
    const float* modulations = (const float*)d_in[0]; // [1024, 256]
    const float* x           = (const float*)d_in[1]; // [1024, 512]
    const float* weight      = (const float*)d_in[2]; // [512, 512]
    const float* bias        = (const float*)d_in[3]; // [512]
    const float* mod_w       = (const float*)d_in[4]; // [512, 256]
    const float* mod_b       = (const float*)d_in[5]; // [512]
    float* out = (float*)d_out;                       // [1024, 512]

    fused_v10<<<64, 1024, 0, stream>>>(
        modulations, x, weight, bias, mod_w, mod_b, out);
}